// Round 1
// baseline (458.158 us; speedup 1.0000x reference)
//
#include <hip/hip_runtime.h>
#include <hip/hip_bf16.h>

// ---------------------------------------------------------------------------
// MHA forward: fp32 I/O, bf16 MFMA compute. B=4,S=2048,D=1024,H=16,DK=64.
//   0. convert all inputs fp32 -> bf16 (Xb staging buffer reused serially)
//   1. Qh = Q@Wq^T+bq  -> [B,H,S,64]      (bf16 GEMM, global_load_lds)
//   2. Kh likewise; Vt = (V@Wv^T+bv)^T -> [B,H,64,S]  (operand-swapped GEMM)
//   3. flash attention (sum-only softmax; swapped QK^T, in-register P)
//   4. out = ctx@Wo^T+bo (fp32 store)
// ---------------------------------------------------------------------------

typedef float  f32x4  __attribute__((ext_vector_type(4)));
typedef __bf16 bf16x8 __attribute__((ext_vector_type(8)));
typedef short  s16x8  __attribute__((ext_vector_type(8)));
typedef int    i32x4  __attribute__((ext_vector_type(4)));

#define MFMA16(a,b,c) __builtin_amdgcn_mfma_f32_16x16x32_bf16((a),(b),(c),0,0,0)

__device__ __forceinline__ unsigned short f2bf(float f) {
    union { float f; unsigned u; } v; v.f = f;
    unsigned r = v.u + 0x7fffu + ((v.u >> 16) & 1u);   // RNE
    return (unsigned short)(r >> 16);
}

__device__ __forceinline__ s16x8 cvt8(const float* __restrict__ p) {
    f32x4 x = *(const f32x4*)p;
    f32x4 y = *(const f32x4*)(p + 4);
    s16x8 r;
    r[0] = (short)f2bf(x[0]); r[1] = (short)f2bf(x[1]);
    r[2] = (short)f2bf(x[2]); r[3] = (short)f2bf(x[3]);
    r[4] = (short)f2bf(y[0]); r[5] = (short)f2bf(y[1]);
    r[6] = (short)f2bf(y[2]); r[7] = (short)f2bf(y[3]);
    return r;
}

// async global->LDS, 16 B per lane; LDS dest = wave-uniform base + lane*16
__device__ __forceinline__ void gl_lds16(const void* g, void* l) {
    __builtin_amdgcn_global_load_lds(
        (const __attribute__((address_space(1))) unsigned int*)g,
        (__attribute__((address_space(3))) unsigned int*)l, 16, 0, 0);
}

// pack 2 f32 -> 1 dword of 2 bf16 (RNE). D[15:0]=bf16(lo), D[31:16]=bf16(hi)
__device__ __forceinline__ int cvtpk_bf16(float lo, float hi) {
    int r;
    asm("v_cvt_pk_bf16_f32 %0, %1, %2" : "=v"(r) : "v"(lo), "v"(hi));
    return r;
}
// a.row1(32 lanes) <-> b.row0: a'=[a.lo32,b.lo32], b'=[a.hi32,b.hi32]
__device__ __forceinline__ void plswap32(int& a, int& b) {
    asm("v_permlane32_swap_b32 %0, %1" : "+v"(a), "+v"(b));
}
// odd 16-rows of a <-> even 16-rows of b:
// a'=[a.r0,b.r0,a.r2,b.r2], b'=[a.r1,b.r1,a.r3,b.r3]
__device__ __forceinline__ void plswap16(int& a, int& b) {
    asm("v_permlane16_swap_b32 %0, %1" : "+v"(a), "+v"(b));
}

// ---------------------------------------------------------------------------
__global__ __launch_bounds__(256) void cvt_kernel(
    const float* __restrict__ src, unsigned short* __restrict__ dst, int n8)
{
    int i = blockIdx.x * 256 + threadIdx.x;
    if (i < n8) *(s16x8*)(dst + (size_t)i * 8) = cvt8(src + (size_t)i * 8);
}

// ---------------------------------------------------------------------------
// bf16 NT GEMM, 128x128 tile, BK=32, global_load_lds staging (m97 pattern).
// D[m,n] = sum_k A[m,k]*W[n,k] + bias
// MODE 0: bias[n]; head-split store [B,H,S,64]           (Q,K projections)
// MODE 1: bias[n]; flat fp32 store [M,1024]              (output projection)
// MODE 2: bias[m]; transposed store [B,H,64,S]           (V: A=Wv, W=V)
// ---------------------------------------------------------------------------
template <int MODE>
__global__ __launch_bounds__(256) void gemm_bf16(
    const unsigned short* __restrict__ A,
    const unsigned short* __restrict__ W,
    const float* __restrict__ bias,
    void* __restrict__ Cv)
{
    constexpr int K = 1024;
    __shared__ unsigned short Ash[128 * 32];
    __shared__ unsigned short Bsh[128 * 32];

    const int t    = threadIdx.x;
    const int w    = t >> 6;
    const int lane = t & 63;
    const int wm   = w >> 1, wn = w & 1;
    const int lr   = lane & 15, quad = lane >> 4;

    const int m0 = blockIdx.y * 128;
    const int n0 = blockIdx.x * 128;

    // staging chunk c = t: LDS offset c*16 B -> row = t>>2 (32-short rows), kchunk=(t&3)*8
    const int srow = t >> 2;
    const int skp  = (t & 3) * 8;

    const unsigned short* Ap0 = A + (size_t)(m0 + srow) * K + skp;
    const unsigned short* Ap1 = Ap0 + (size_t)64 * K;
    const unsigned short* Wp0 = W + (size_t)(n0 + srow) * K + skp;
    const unsigned short* Wp1 = Wp0 + (size_t)64 * K;
    unsigned short* lA0 = &Ash[w * 512];           // wave-uniform bases
    unsigned short* lA1 = &Ash[2048 + w * 512];
    unsigned short* lB0 = &Bsh[w * 512];
    unsigned short* lB1 = &Bsh[2048 + w * 512];

    f32x4 acc[4][4] = {};

    for (int k0 = 0; k0 < K; k0 += 32) {
        __syncthreads();                 // all waves done reading prior tile
        gl_lds16(Ap0 + k0, lA0);
        gl_lds16(Ap1 + k0, lA1);
        gl_lds16(Wp0 + k0, lB0);
        gl_lds16(Wp1 + k0, lB1);
        __syncthreads();                 // drains vmcnt -> tile visible

        bf16x8 af[4], bw[4];
#pragma unroll
        for (int i = 0; i < 4; i++)
            af[i] = *(const bf16x8*)&Ash[(wm * 64 + i * 16 + lr) * 32 + quad * 8];
#pragma unroll
        for (int j = 0; j < 4; j++)
            bw[j] = *(const bf16x8*)&Bsh[(wn * 64 + j * 16 + lr) * 32 + quad * 8];

#pragma unroll
        for (int i = 0; i < 4; i++)
#pragma unroll
            for (int j = 0; j < 4; j++)
                acc[i][j] = MFMA16(af[i], bw[j], acc[i][j]);
    }

    // epilogue: C/D row = quad*4+r (m-side), col = lr (n-side)
#pragma unroll
    for (int i = 0; i < 4; i++) {
#pragma unroll
        for (int j = 0; j < 4; j++) {
            const int n = n0 + wn * 64 + j * 16 + lr;
#pragma unroll
            for (int r = 0; r < 4; r++) {
                const int m = m0 + wm * 64 + i * 16 + quad * 4 + r;
                float val = acc[i][j][r] + ((MODE == 2) ? bias[m] : bias[n]);
                if (MODE == 0) {
                    const int b = m >> 11, s = m & 2047, h = n >> 6, d = n & 63;
                    ((unsigned short*)Cv)[(((size_t)(b * 16 + h) * 2048 + s) << 6) + d] = f2bf(val);
                } else if (MODE == 1) {
                    ((float*)Cv)[(size_t)m * 1024 + n] = val;
                } else {
                    const int h = m >> 6, d = m & 63, b = n >> 11, s = n & 2047;
                    ((unsigned short*)Cv)[((size_t)(b * 16 + h) * 64 + d) * 2048 + s] = f2bf(val);
                }
            }
        }
    }
}

// ---------------------------------------------------------------------------
// Flash attention (sum-only softmax). Qh,Kh [B,H,S,64]; Vt [B,H,64,S] bf16.
// ctx out [B,S,1024] bf16. Grid (32,64), 4 waves, 16 q/wave, BK=64.
// LDS rows stride KS=72 shorts (144 B: b128-aligned, conflict-free patterns).
//
// Swapped QK^T (T12): compute MFMA(K_frag, Q_frag) -> S^T tile, so lane
// (quad,lr) holds S[k=16*nt+4*quad+r][q=lr] — the k-axis is lane-local.
// P=exp(S/8) stays in registers; PV A-fragments (lane needs P[q=lr][k=
// 8*quad+j]) are rebuilt with cvt_pk + permlane32_swap + permlane16_swap:
//   A=pack(nt even), B=pack(nt odd);
//   after plswap32: A2=[A.lo,B.lo], B2=[A.hi,B.hi]
//   after plswap16(A2,B2): ret0 = W(j0,j1) dword, ret1 = W(j4,j5) dword
// (verified per-quad: q0:A2 self / q1:B2[l^16] / q2:A2 self / q3:B2[l-16]).
// No Psh LDS, no lgkm drain, no scalar b16 scatter. LDS 18432 B -> 8 blk/CU.
// ---------------------------------------------------------------------------
__global__ __launch_bounds__(256) void attn_kernel(
    const unsigned short* __restrict__ Qh,
    const unsigned short* __restrict__ Kh,
    const unsigned short* __restrict__ Vt,
    unsigned short* __restrict__ ctx)
{
    constexpr int KS = 72;
    __shared__ unsigned short Ksh[64 * KS];     // [k][d]
    __shared__ unsigned short Vts[64 * KS];     // [d][k]

    const int t    = threadIdx.x;
    const int w    = t >> 6;
    const int lane = t & 63;
    const int lr   = lane & 15, quad = lane >> 4;

    const int bh = blockIdx.y, qblk = blockIdx.x;
    const size_t base = (size_t)bh * 2048 * 64;
    const unsigned short* Qp = Qh + base;
    const unsigned short* Kg = Kh + base + (size_t)lane * 64 + w * 16;
    const unsigned short* Vg = Vt + base + (size_t)lane * 2048 + w * 16;

    const int q0 = qblk * 64 + w * 16;
    bf16x8 aq0 = *(const bf16x8*)(Qp + (size_t)(q0 + lr) * 64 + quad * 8);
    bf16x8 aq1 = *(const bf16x8*)(Qp + (size_t)(q0 + lr) * 64 + 32 + quad * 8);

    f32x4 Of[4] = {};
    float lsum = 0.f;

    for (int kb = 0; kb < 2048; kb += 64) {
        s16x8 kv0 = *(const s16x8*)(Kg + (size_t)kb * 64);
        s16x8 kv1 = *(const s16x8*)(Kg + (size_t)kb * 64 + 8);
        s16x8 vv0 = *(const s16x8*)(Vg + kb);
        s16x8 vv1 = *(const s16x8*)(Vg + kb + 8);

        __syncthreads();   // prior iteration's LDS reads complete
        *(s16x8*)&Ksh[lane * KS + w * 16]     = kv0;
        *(s16x8*)&Ksh[lane * KS + w * 16 + 8] = kv1;
        *(s16x8*)&Vts[lane * KS + w * 16]     = vv0;
        *(s16x8*)&Vts[lane * KS + w * 16 + 8] = vv1;
        __syncthreads();

        // ---- swapped QK^T: same LDS reads as before, operands exchanged.
        // lane holds S[k=16*nt+4*quad+r][q=lr] in pe[nt][r] after exp.
        f32x4 pe[4];
#pragma unroll
        for (int nt = 0; nt < 4; nt++) {
            const unsigned short* kr = &Ksh[(16 * nt + lr) * KS + quad * 8];
            f32x4 c = {};
            c = MFMA16(*(const bf16x8*)kr, aq0, c);
            c = MFMA16(*(const bf16x8*)(kr + 32), aq1, c);
            f32x4 p;
#pragma unroll
            for (int r = 0; r < 4; r++) p[r] = __expf(c[r] * 0.125f);
            lsum += (p[0] + p[1]) + (p[2] + p[3]);
            pe[nt] = p;
        }

        // ---- PV A-fragments in-register (no LDS round-trip)
        // half 0: k 0..31 from pe[0] (A) and pe[1] (B)
        int a0 = cvtpk_bf16(pe[0][0], pe[0][1]);
        int a1 = cvtpk_bf16(pe[0][2], pe[0][3]);
        int b0 = cvtpk_bf16(pe[1][0], pe[1][1]);
        int b1 = cvtpk_bf16(pe[1][2], pe[1][3]);
        plswap32(a0, b0); plswap32(a1, b1);
        plswap16(a0, b0); plswap16(a1, b1);
        // a0=W(k pair j0), a1=W(j2), b0=W(j4), b1=W(j6)
        i32x4 f0; f0[0] = a0; f0[1] = a1; f0[2] = b0; f0[3] = b1;

        // half 1: k 32..63 from pe[2] (A) and pe[3] (B)
        int c0 = cvtpk_bf16(pe[2][0], pe[2][1]);
        int c1 = cvtpk_bf16(pe[2][2], pe[2][3]);
        int d0 = cvtpk_bf16(pe[3][0], pe[3][1]);
        int d1 = cvtpk_bf16(pe[3][2], pe[3][3]);
        plswap32(c0, d0); plswap32(c1, d1);
        plswap16(c0, d0); plswap16(c1, d1);
        i32x4 f1; f1[0] = c0; f1[1] = c1; f1[2] = d0; f1[3] = d1;

        bf16x8 pf0 = __builtin_bit_cast(bf16x8, f0);
        bf16x8 pf1 = __builtin_bit_cast(bf16x8, f1);

        // ---- PV : O[q][d] += P[q][k] * V[k][d]
#pragma unroll
        for (int dt = 0; dt < 4; dt++) {
            const unsigned short* vr = &Vts[(dt * 16 + lr) * KS + quad * 8];
            Of[dt] = MFMA16(pf0, *(const bf16x8*)vr, Of[dt]);
            Of[dt] = MFMA16(pf1, *(const bf16x8*)(vr + 32), Of[dt]);
        }
    }

    // lane's lsum covers k={16nt+4quad+r} for q=lr; sum across quads -> all k
    lsum += __shfl_xor(lsum, 16);
    lsum += __shfl_xor(lsum, 32);
    // every lane (quad,lr) now holds total sum for q-row lr

    const int b = bh >> 4, h = bh & 15;
#pragma unroll
    for (int r = 0; r < 4; r++) {
        // O rows are q=4*quad+r; fetch that row's sum from lane (4*quad+r)
        const float inv = 1.0f / __shfl(lsum, quad * 4 + r, 64);
        const int q = q0 + quad * 4 + r;
        unsigned short* cp = ctx + ((size_t)b * 2048 + q) * 1024 + h * 64;
#pragma unroll
        for (int dt = 0; dt < 4; dt++)
            cp[dt * 16 + lr] = f2bf(Of[dt][r] * inv);
    }
}

// ---------------------------------------------------------------------------
extern "C" void kernel_launch(void* const* d_in, const int* in_sizes, int n_in,
                              void* d_out, int out_size, void* d_ws, size_t ws_size,
                              hipStream_t stream) {
    const float* Q  = (const float*)d_in[0];
    const float* K  = (const float*)d_in[1];
    const float* V  = (const float*)d_in[2];
    const float* Wq = (const float*)d_in[3];
    const float* bq = (const float*)d_in[4];
    const float* Wk = (const float*)d_in[5];
    const float* bk = (const float*)d_in[6];
    const float* Wv = (const float*)d_in[7];
    const float* bv = (const float*)d_in[8];
    const float* Wo = (const float*)d_in[9];
    const float* bo = (const float*)d_in[10];

    // workspace (bf16 elements). Xb reused serially for Q,K,V; Ctx aliases Xb.
    const size_t EB = (size_t)8192 * 1024;   // big tensor elems
    const size_t EW = (size_t)1024 * 1024;   // weight elems
    unsigned short* Xb  = (unsigned short*)d_ws;
    unsigned short* Wqb = Xb  + EB;
    unsigned short* Wkb = Wqb + EW;
    unsigned short* Wvb = Wkb + EW;
    unsigned short* Wob = Wvb + EW;
    unsigned short* Qh  = Wob + EW;
    unsigned short* Kh  = Qh  + EB;
    unsigned short* Vtw = Kh  + EB;
    unsigned short* Ctx = Xb;                 // Xb dead after V-GEMM

    const int n8b = (int)(EB / 8);            // 1048576
    const int n8w = (int)(EW / 8);            // 131072

    cvt_kernel<<<n8w / 256, 256, 0, stream>>>(Wq, Wqb, n8w);
    cvt_kernel<<<n8w / 256, 256, 0, stream>>>(Wk, Wkb, n8w);
    cvt_kernel<<<n8w / 256, 256, 0, stream>>>(Wv, Wvb, n8w);
    cvt_kernel<<<n8w / 256, 256, 0, stream>>>(Wo, Wob, n8w);

    dim3 tb(256), gP(8, 64), gT(64, 8);

    cvt_kernel<<<n8b / 256, 256, 0, stream>>>(Q, Xb, n8b);
    gemm_bf16<0><<<gP, tb, 0, stream>>>(Xb, Wqb, bq, Qh);

    cvt_kernel<<<n8b / 256, 256, 0, stream>>>(K, Xb, n8b);
    gemm_bf16<0><<<gP, tb, 0, stream>>>(Xb, Wkb, bk, Kh);

    cvt_kernel<<<n8b / 256, 256, 0, stream>>>(V, Xb, n8b);
    gemm_bf16<2><<<gT, tb, 0, stream>>>(Wvb, Xb, bv, Vtw);   // emits V^T layout

    attn_kernel<<<dim3(32, 64), tb, 0, stream>>>(Qh, Kh, Vtw, Ctx);

    gemm_bf16<1><<<gP, tb, 0, stream>>>(Ctx, Wob, bo, (float*)d_out);
}

// Round 2
// 422.364 us; speedup vs baseline: 1.0847x; 1.0847x over previous
//
#include <hip/hip_runtime.h>
#include <hip/hip_bf16.h>

// ---------------------------------------------------------------------------
// MHA forward: fp32 I/O, bf16 MFMA compute. B=4,S=2048,D=1024,H=16,DK=64.
//   0. convert all inputs fp32 -> bf16 (Xb staging buffer reused serially)
//   1. Qh = Q@Wq^T+bq  -> [B,H,S,64]      (bf16 GEMM, global_load_lds)
//   2. Kh likewise; Vt = (V@Wv^T+bv)^T -> [B,H,64,S]  (operand-swapped GEMM)
//   3. flash attention (sum-only softmax; swapped QK^T, in-register P,
//      T14 async-stage: K/V tile kb+1 loads issue under tile kb's compute)
//   4. out = ctx@Wo^T+bo (fp32 store)
// ---------------------------------------------------------------------------

typedef float  f32x4  __attribute__((ext_vector_type(4)));
typedef __bf16 bf16x8 __attribute__((ext_vector_type(8)));
typedef short  s16x8  __attribute__((ext_vector_type(8)));
typedef int    i32x4  __attribute__((ext_vector_type(4)));

#define MFMA16(a,b,c) __builtin_amdgcn_mfma_f32_16x16x32_bf16((a),(b),(c),0,0,0)

__device__ __forceinline__ unsigned short f2bf(float f) {
    union { float f; unsigned u; } v; v.f = f;
    unsigned r = v.u + 0x7fffu + ((v.u >> 16) & 1u);   // RNE
    return (unsigned short)(r >> 16);
}

__device__ __forceinline__ s16x8 cvt8(const float* __restrict__ p) {
    f32x4 x = *(const f32x4*)p;
    f32x4 y = *(const f32x4*)(p + 4);
    s16x8 r;
    r[0] = (short)f2bf(x[0]); r[1] = (short)f2bf(x[1]);
    r[2] = (short)f2bf(x[2]); r[3] = (short)f2bf(x[3]);
    r[4] = (short)f2bf(y[0]); r[5] = (short)f2bf(y[1]);
    r[6] = (short)f2bf(y[2]); r[7] = (short)f2bf(y[3]);
    return r;
}

// async global->LDS, 16 B per lane; LDS dest = wave-uniform base + lane*16
__device__ __forceinline__ void gl_lds16(const void* g, void* l) {
    __builtin_amdgcn_global_load_lds(
        (const __attribute__((address_space(1))) unsigned int*)g,
        (__attribute__((address_space(3))) unsigned int*)l, 16, 0, 0);
}

// pack 2 f32 -> 1 dword of 2 bf16 (RNE). D[15:0]=bf16(lo), D[31:16]=bf16(hi)
__device__ __forceinline__ int cvtpk_bf16(float lo, float hi) {
    int r;
    asm("v_cvt_pk_bf16_f32 %0, %1, %2" : "=v"(r) : "v"(lo), "v"(hi));
    return r;
}
// a.row1(32 lanes) <-> b.row0: a'=[a.lo32,b.lo32], b'=[a.hi32,b.hi32]
__device__ __forceinline__ void plswap32(int& a, int& b) {
    asm("v_permlane32_swap_b32 %0, %1" : "+v"(a), "+v"(b));
}
// odd 16-rows of a <-> even 16-rows of b:
// a'=[a.r0,b.r0,a.r2,b.r2], b'=[a.r1,b.r1,a.r3,b.r3]
__device__ __forceinline__ void plswap16(int& a, int& b) {
    asm("v_permlane16_swap_b32 %0, %1" : "+v"(a), "+v"(b));
}

// ---------------------------------------------------------------------------
__global__ __launch_bounds__(256) void cvt_kernel(
    const float* __restrict__ src, unsigned short* __restrict__ dst, int n8)
{
    int i = blockIdx.x * 256 + threadIdx.x;
    if (i < n8) *(s16x8*)(dst + (size_t)i * 8) = cvt8(src + (size_t)i * 8);
}

// ---------------------------------------------------------------------------
// bf16 NT GEMM, 128x128 tile, BK=32, global_load_lds staging (m97 pattern).
// D[m,n] = sum_k A[m,k]*W[n,k] + bias
// MODE 0: bias[n]; head-split store [B,H,S,64]           (Q,K projections)
// MODE 1: bias[n]; flat fp32 store [M,1024]              (output projection)
// MODE 2: bias[m]; transposed store [B,H,64,S]           (V: A=Wv, W=V)
// ---------------------------------------------------------------------------
template <int MODE>
__global__ __launch_bounds__(256) void gemm_bf16(
    const unsigned short* __restrict__ A,
    const unsigned short* __restrict__ W,
    const float* __restrict__ bias,
    void* __restrict__ Cv)
{
    constexpr int K = 1024;
    __shared__ unsigned short Ash[128 * 32];
    __shared__ unsigned short Bsh[128 * 32];

    const int t    = threadIdx.x;
    const int w    = t >> 6;
    const int lane = t & 63;
    const int wm   = w >> 1, wn = w & 1;
    const int lr   = lane & 15, quad = lane >> 4;

    const int m0 = blockIdx.y * 128;
    const int n0 = blockIdx.x * 128;

    // staging chunk c = t: LDS offset c*16 B -> row = t>>2 (32-short rows), kchunk=(t&3)*8
    const int srow = t >> 2;
    const int skp  = (t & 3) * 8;

    const unsigned short* Ap0 = A + (size_t)(m0 + srow) * K + skp;
    const unsigned short* Ap1 = Ap0 + (size_t)64 * K;
    const unsigned short* Wp0 = W + (size_t)(n0 + srow) * K + skp;
    const unsigned short* Wp1 = Wp0 + (size_t)64 * K;
    unsigned short* lA0 = &Ash[w * 512];           // wave-uniform bases
    unsigned short* lA1 = &Ash[2048 + w * 512];
    unsigned short* lB0 = &Bsh[w * 512];
    unsigned short* lB1 = &Bsh[2048 + w * 512];

    f32x4 acc[4][4] = {};

    for (int k0 = 0; k0 < K; k0 += 32) {
        __syncthreads();                 // all waves done reading prior tile
        gl_lds16(Ap0 + k0, lA0);
        gl_lds16(Ap1 + k0, lA1);
        gl_lds16(Wp0 + k0, lB0);
        gl_lds16(Wp1 + k0, lB1);
        __syncthreads();                 // drains vmcnt -> tile visible

        bf16x8 af[4], bw[4];
#pragma unroll
        for (int i = 0; i < 4; i++)
            af[i] = *(const bf16x8*)&Ash[(wm * 64 + i * 16 + lr) * 32 + quad * 8];
#pragma unroll
        for (int j = 0; j < 4; j++)
            bw[j] = *(const bf16x8*)&Bsh[(wn * 64 + j * 16 + lr) * 32 + quad * 8];

#pragma unroll
        for (int i = 0; i < 4; i++)
#pragma unroll
            for (int j = 0; j < 4; j++)
                acc[i][j] = MFMA16(af[i], bw[j], acc[i][j]);
    }

    // epilogue: C/D row = quad*4+r (m-side), col = lr (n-side)
#pragma unroll
    for (int i = 0; i < 4; i++) {
#pragma unroll
        for (int j = 0; j < 4; j++) {
            const int n = n0 + wn * 64 + j * 16 + lr;
#pragma unroll
            for (int r = 0; r < 4; r++) {
                const int m = m0 + wm * 64 + i * 16 + quad * 4 + r;
                float val = acc[i][j][r] + ((MODE == 2) ? bias[m] : bias[n]);
                if (MODE == 0) {
                    const int b = m >> 11, s = m & 2047, h = n >> 6, d = n & 63;
                    ((unsigned short*)Cv)[(((size_t)(b * 16 + h) * 2048 + s) << 6) + d] = f2bf(val);
                } else if (MODE == 1) {
                    ((float*)Cv)[(size_t)m * 1024 + n] = val;
                } else {
                    const int h = m >> 6, d = m & 63, b = n >> 11, s = n & 2047;
                    ((unsigned short*)Cv)[((size_t)(b * 16 + h) * 64 + d) * 2048 + s] = f2bf(val);
                }
            }
        }
    }
}

// ---------------------------------------------------------------------------
// Flash attention (sum-only softmax). Qh,Kh [B,H,S,64]; Vt [B,H,64,S] bf16.
// ctx out [B,S,1024] bf16. Grid (32,64), 4 waves, 16 q/wave, BK=64.
// LDS rows stride KS=72 shorts (144 B: b128-aligned, conflict-free patterns).
//
// Swapped QK^T (T12): lane (quad,lr) holds S[k=16*nt+4*quad+r][q=lr]; P stays
// in registers, PV A-frags rebuilt via cvt_pk + permlane32/16_swap (no Psh).
//
// T14 async-stage: regs for tile kb loaded during tile kb-64's compute;
// written to LDS after barrier (vmcnt long since retired), then loads for
// kb+64 issue BEFORE the second barrier -> full compute phase hides latency.
// ---------------------------------------------------------------------------
__global__ __launch_bounds__(256) void attn_kernel(
    const unsigned short* __restrict__ Qh,
    const unsigned short* __restrict__ Kh,
    const unsigned short* __restrict__ Vt,
    unsigned short* __restrict__ ctx)
{
    constexpr int KS = 72;
    __shared__ unsigned short Ksh[64 * KS];     // [k][d]
    __shared__ unsigned short Vts[64 * KS];     // [d][k]

    const int t    = threadIdx.x;
    const int w    = t >> 6;
    const int lane = t & 63;
    const int lr   = lane & 15, quad = lane >> 4;

    const int bh = blockIdx.y, qblk = blockIdx.x;
    const size_t base = (size_t)bh * 2048 * 64;
    const unsigned short* Qp = Qh + base;
    const unsigned short* Kg = Kh + base + (size_t)lane * 64 + w * 16;
    const unsigned short* Vg = Vt + base + (size_t)lane * 2048 + w * 16;

    const int q0 = qblk * 64 + w * 16;
    bf16x8 aq0 = *(const bf16x8*)(Qp + (size_t)(q0 + lr) * 64 + quad * 8);
    bf16x8 aq1 = *(const bf16x8*)(Qp + (size_t)(q0 + lr) * 64 + 32 + quad * 8);

    f32x4 Of[4] = {};
    float lsum = 0.f;

    // prologue: prefetch tile kb=0
    s16x8 kv0 = *(const s16x8*)(Kg);
    s16x8 kv1 = *(const s16x8*)(Kg + 8);
    s16x8 vv0 = *(const s16x8*)(Vg);
    s16x8 vv1 = *(const s16x8*)(Vg + 8);

    for (int kb = 0; kb < 2048; kb += 64) {
        __syncthreads();   // prior iteration's LDS reads complete
        *(s16x8*)&Ksh[lane * KS + w * 16]     = kv0;
        *(s16x8*)&Ksh[lane * KS + w * 16 + 8] = kv1;
        *(s16x8*)&Vts[lane * KS + w * 16]     = vv0;
        *(s16x8*)&Vts[lane * KS + w * 16 + 8] = vv1;

        // issue next tile's loads now; consumed at NEXT iteration's ds_write,
        // i.e. after this iteration's full compute phase (latency hidden).
        const int kn = (kb + 64) & 2047;     // wraps to 0 on last iter (unused)
        kv0 = *(const s16x8*)(Kg + (size_t)kn * 64);
        kv1 = *(const s16x8*)(Kg + (size_t)kn * 64 + 8);
        vv0 = *(const s16x8*)(Vg + kn);
        vv1 = *(const s16x8*)(Vg + kn + 8);

        __syncthreads();   // staged tile visible

        // ---- swapped QK^T: lane holds S[k=16*nt+4*quad+r][q=lr]
        f32x4 pe[4];
#pragma unroll
        for (int nt = 0; nt < 4; nt++) {
            const unsigned short* kr = &Ksh[(16 * nt + lr) * KS + quad * 8];
            f32x4 c = {};
            c = MFMA16(*(const bf16x8*)kr, aq0, c);
            c = MFMA16(*(const bf16x8*)(kr + 32), aq1, c);
            f32x4 p;
#pragma unroll
            for (int r = 0; r < 4; r++) p[r] = __expf(c[r] * 0.125f);
            lsum += (p[0] + p[1]) + (p[2] + p[3]);
            pe[nt] = p;
        }

        // ---- PV A-fragments in-register (no LDS round-trip)
        // half 0: k 0..31 from pe[0] (A) and pe[1] (B)
        int a0 = cvtpk_bf16(pe[0][0], pe[0][1]);
        int a1 = cvtpk_bf16(pe[0][2], pe[0][3]);
        int b0 = cvtpk_bf16(pe[1][0], pe[1][1]);
        int b1 = cvtpk_bf16(pe[1][2], pe[1][3]);
        plswap32(a0, b0); plswap32(a1, b1);
        plswap16(a0, b0); plswap16(a1, b1);
        i32x4 f0; f0[0] = a0; f0[1] = a1; f0[2] = b0; f0[3] = b1;

        // half 1: k 32..63 from pe[2] (A) and pe[3] (B)
        int c0 = cvtpk_bf16(pe[2][0], pe[2][1]);
        int c1 = cvtpk_bf16(pe[2][2], pe[2][3]);
        int d0 = cvtpk_bf16(pe[3][0], pe[3][1]);
        int d1 = cvtpk_bf16(pe[3][2], pe[3][3]);
        plswap32(c0, d0); plswap32(c1, d1);
        plswap16(c0, d0); plswap16(c1, d1);
        i32x4 f1; f1[0] = c0; f1[1] = c1; f1[2] = d0; f1[3] = d1;

        bf16x8 pf0 = __builtin_bit_cast(bf16x8, f0);
        bf16x8 pf1 = __builtin_bit_cast(bf16x8, f1);

        // ---- PV : O[q][d] += P[q][k] * V[k][d]
#pragma unroll
        for (int dt = 0; dt < 4; dt++) {
            const unsigned short* vr = &Vts[(dt * 16 + lr) * KS + quad * 8];
            Of[dt] = MFMA16(pf0, *(const bf16x8*)vr, Of[dt]);
            Of[dt] = MFMA16(pf1, *(const bf16x8*)(vr + 32), Of[dt]);
        }
    }

    // lane's lsum covers k={16nt+4quad+r} for q=lr; sum across quads -> all k
    lsum += __shfl_xor(lsum, 16);
    lsum += __shfl_xor(lsum, 32);
    // every lane (quad,lr) now holds total sum for q-row lr

    const int b = bh >> 4, h = bh & 15;
#pragma unroll
    for (int r = 0; r < 4; r++) {
        // O rows are q=4*quad+r; fetch that row's sum from lane (4*quad+r)
        const float inv = 1.0f / __shfl(lsum, quad * 4 + r, 64);
        const int q = q0 + quad * 4 + r;
        unsigned short* cp = ctx + ((size_t)b * 2048 + q) * 1024 + h * 64;
#pragma unroll
        for (int dt = 0; dt < 4; dt++)
            cp[dt * 16 + lr] = f2bf(Of[dt][r] * inv);
    }
}

// ---------------------------------------------------------------------------
extern "C" void kernel_launch(void* const* d_in, const int* in_sizes, int n_in,
                              void* d_out, int out_size, void* d_ws, size_t ws_size,
                              hipStream_t stream) {
    const float* Q  = (const float*)d_in[0];
    const float* K  = (const float*)d_in[1];
    const float* V  = (const float*)d_in[2];
    const float* Wq = (const float*)d_in[3];
    const float* bq = (const float*)d_in[4];
    const float* Wk = (const float*)d_in[5];
    const float* bk = (const float*)d_in[6];
    const float* Wv = (const float*)d_in[7];
    const float* bv = (const float*)d_in[8];
    const float* Wo = (const float*)d_in[9];
    const float* bo = (const float*)d_in[10];

    // workspace (bf16 elements). Xb reused serially for Q,K,V; Ctx aliases Xb.
    const size_t EB = (size_t)8192 * 1024;   // big tensor elems
    const size_t EW = (size_t)1024 * 1024;   // weight elems
    unsigned short* Xb  = (unsigned short*)d_ws;
    unsigned short* Wqb = Xb  + EB;
    unsigned short* Wkb = Wqb + EW;
    unsigned short* Wvb = Wkb + EW;
    unsigned short* Wob = Wvb + EW;
    unsigned short* Qh  = Wob + EW;
    unsigned short* Kh  = Qh  + EB;
    unsigned short* Vtw = Kh  + EB;
    unsigned short* Ctx = Xb;                 // Xb dead after V-GEMM

    const int n8b = (int)(EB / 8);            // 1048576
    const int n8w = (int)(EW / 8);            // 131072

    cvt_kernel<<<n8w / 256, 256, 0, stream>>>(Wq, Wqb, n8w);
    cvt_kernel<<<n8w / 256, 256, 0, stream>>>(Wk, Wkb, n8w);
    cvt_kernel<<<n8w / 256, 256, 0, stream>>>(Wv, Wvb, n8w);
    cvt_kernel<<<n8w / 256, 256, 0, stream>>>(Wo, Wob, n8w);

    dim3 tb(256), gP(8, 64), gT(64, 8);

    cvt_kernel<<<n8b / 256, 256, 0, stream>>>(Q, Xb, n8b);
    gemm_bf16<0><<<gP, tb, 0, stream>>>(Xb, Wqb, bq, Qh);

    cvt_kernel<<<n8b / 256, 256, 0, stream>>>(K, Xb, n8b);
    gemm_bf16<0><<<gP, tb, 0, stream>>>(Xb, Wkb, bk, Kh);

    cvt_kernel<<<n8b / 256, 256, 0, stream>>>(V, Xb, n8b);
    gemm_bf16<2><<<gT, tb, 0, stream>>>(Wvb, Xb, bv, Vtw);   // emits V^T layout

    attn_kernel<<<dim3(32, 64), tb, 0, stream>>>(Qh, Kh, Vtw, Ctx);

    gemm_bf16<1><<<gP, tb, 0, stream>>>(Ctx, Wob, bo, (float*)d_out);
}

// Round 4
// 373.008 us; speedup vs baseline: 1.2283x; 1.1323x over previous
//
#include <hip/hip_runtime.h>
#include <hip/hip_bf16.h>

// ---------------------------------------------------------------------------
// MHA forward: fp32 I/O, bf16 MFMA compute. B=4,S=2048,D=1024,H=16,DK=64.
//   0. convert all inputs fp32 -> bf16 (Xb staging buffer reused serially)
//   1. Qh = (Q@Wq^T+bq)*0.125*log2e -> [B,H,S,64]  (scale folded for exp2)
//   2. Kh likewise (scale=1); Vt = (V@Wv^T+bv)^T -> [B,H,64,S]
//   3. flash attention (sum-only softmax; swapped QK^T, in-register P,
//      T14 async-stage, 32 q-rows/wave: K/V LDS reads amortized 2x)
//   4. out = ctx@Wo^T+bo (fp32 store)
// ---------------------------------------------------------------------------

typedef float  f32x4  __attribute__((ext_vector_type(4)));
typedef __bf16 bf16x8 __attribute__((ext_vector_type(8)));
typedef short  s16x8  __attribute__((ext_vector_type(8)));
typedef int    i32x4  __attribute__((ext_vector_type(4)));

#define MFMA16(a,b,c) __builtin_amdgcn_mfma_f32_16x16x32_bf16((a),(b),(c),0,0,0)

__device__ __forceinline__ unsigned short f2bf(float f) {
    union { float f; unsigned u; } v; v.f = f;
    unsigned r = v.u + 0x7fffu + ((v.u >> 16) & 1u);   // RNE
    return (unsigned short)(r >> 16);
}

__device__ __forceinline__ s16x8 cvt8(const float* __restrict__ p) {
    f32x4 x = *(const f32x4*)p;
    f32x4 y = *(const f32x4*)(p + 4);
    s16x8 r;
    r[0] = (short)f2bf(x[0]); r[1] = (short)f2bf(x[1]);
    r[2] = (short)f2bf(x[2]); r[3] = (short)f2bf(x[3]);
    r[4] = (short)f2bf(y[0]); r[5] = (short)f2bf(y[1]);
    r[6] = (short)f2bf(y[2]); r[7] = (short)f2bf(y[3]);
    return r;
}

// async global->LDS, 16 B per lane; LDS dest = wave-uniform base + lane*16
__device__ __forceinline__ void gl_lds16(const void* g, void* l) {
    __builtin_amdgcn_global_load_lds(
        (const __attribute__((address_space(1))) unsigned int*)g,
        (__attribute__((address_space(3))) unsigned int*)l, 16, 0, 0);
}

// raw v_exp_f32: D = 2^S0
__device__ __forceinline__ float exp2_fast(float x) {
    float r;
    asm("v_exp_f32 %0, %1" : "=v"(r) : "v"(x));
    return r;
}

// pack 2 f32 -> 1 dword of 2 bf16 (RNE). D[15:0]=bf16(lo), D[31:16]=bf16(hi)
__device__ __forceinline__ int cvtpk_bf16(float lo, float hi) {
    int r;
    asm("v_cvt_pk_bf16_f32 %0, %1, %2" : "=v"(r) : "v"(lo), "v"(hi));
    return r;
}
// a.row1(32 lanes) <-> b.row0: a'=[a.lo32,b.lo32], b'=[a.hi32,b.hi32]
__device__ __forceinline__ void plswap32(int& a, int& b) {
    asm("v_permlane32_swap_b32 %0, %1" : "+v"(a), "+v"(b));
}
// odd 16-rows of a <-> even 16-rows of b:
// a'=[a.r0,b.r0,a.r2,b.r2], b'=[a.r1,b.r1,a.r3,b.r3]
__device__ __forceinline__ void plswap16(int& a, int& b) {
    asm("v_permlane16_swap_b32 %0, %1" : "+v"(a), "+v"(b));
}

// P-row (lane-local, S^T layout) -> two PV A-fragment dwords x2
__device__ __forceinline__ void pack_pf(const f32x4 pe[4], bf16x8& pf0, bf16x8& pf1) {
    int a0 = cvtpk_bf16(pe[0][0], pe[0][1]);
    int a1 = cvtpk_bf16(pe[0][2], pe[0][3]);
    int b0 = cvtpk_bf16(pe[1][0], pe[1][1]);
    int b1 = cvtpk_bf16(pe[1][2], pe[1][3]);
    plswap32(a0, b0); plswap32(a1, b1);
    plswap16(a0, b0); plswap16(a1, b1);
    i32x4 f0; f0[0] = a0; f0[1] = a1; f0[2] = b0; f0[3] = b1;
    int c0 = cvtpk_bf16(pe[2][0], pe[2][1]);
    int c1 = cvtpk_bf16(pe[2][2], pe[2][3]);
    int d0 = cvtpk_bf16(pe[3][0], pe[3][1]);
    int d1 = cvtpk_bf16(pe[3][2], pe[3][3]);
    plswap32(c0, d0); plswap32(c1, d1);
    plswap16(c0, d0); plswap16(c1, d1);
    i32x4 f1; f1[0] = c0; f1[1] = c1; f1[2] = d0; f1[3] = d1;
    pf0 = __builtin_bit_cast(bf16x8, f0);
    pf1 = __builtin_bit_cast(bf16x8, f1);
}

// ---------------------------------------------------------------------------
__global__ __launch_bounds__(256) void cvt_kernel(
    const float* __restrict__ src, unsigned short* __restrict__ dst, int n8)
{
    int i = blockIdx.x * 256 + threadIdx.x;
    if (i < n8) *(s16x8*)(dst + (size_t)i * 8) = cvt8(src + (size_t)i * 8);
}

// ---------------------------------------------------------------------------
// bf16 NT GEMM, 128x128 tile, BK=32, global_load_lds staging (m97 pattern).
// D[m,n] = (sum_k A[m,k]*W[n,k] + bias) * scale
// MODE 0: bias[n]; head-split store [B,H,S,64]           (Q,K projections)
// MODE 1: bias[n]; flat fp32 store [M,1024]              (output projection)
// MODE 2: bias[m]; transposed store [B,H,64,S]           (V: A=Wv, W=V)
// ---------------------------------------------------------------------------
template <int MODE>
__global__ __launch_bounds__(256) void gemm_bf16(
    const unsigned short* __restrict__ A,
    const unsigned short* __restrict__ W,
    const float* __restrict__ bias,
    void* __restrict__ Cv, float scale)
{
    constexpr int K = 1024;
    __shared__ unsigned short Ash[128 * 32];
    __shared__ unsigned short Bsh[128 * 32];

    const int t    = threadIdx.x;
    const int w    = t >> 6;
    const int lane = t & 63;
    const int wm   = w >> 1, wn = w & 1;
    const int lr   = lane & 15, quad = lane >> 4;

    const int m0 = blockIdx.y * 128;
    const int n0 = blockIdx.x * 128;

    // staging chunk c = t: LDS offset c*16 B -> row = t>>2 (32-short rows), kchunk=(t&3)*8
    const int srow = t >> 2;
    const int skp  = (t & 3) * 8;

    const unsigned short* Ap0 = A + (size_t)(m0 + srow) * K + skp;
    const unsigned short* Ap1 = Ap0 + (size_t)64 * K;
    const unsigned short* Wp0 = W + (size_t)(n0 + srow) * K + skp;
    const unsigned short* Wp1 = Wp0 + (size_t)64 * K;
    unsigned short* lA0 = &Ash[w * 512];           // wave-uniform bases
    unsigned short* lA1 = &Ash[2048 + w * 512];
    unsigned short* lB0 = &Bsh[w * 512];
    unsigned short* lB1 = &Bsh[2048 + w * 512];

    f32x4 acc[4][4] = {};

    for (int k0 = 0; k0 < K; k0 += 32) {
        __syncthreads();                 // all waves done reading prior tile
        gl_lds16(Ap0 + k0, lA0);
        gl_lds16(Ap1 + k0, lA1);
        gl_lds16(Wp0 + k0, lB0);
        gl_lds16(Wp1 + k0, lB1);
        __syncthreads();                 // drains vmcnt -> tile visible

        bf16x8 af[4], bw[4];
#pragma unroll
        for (int i = 0; i < 4; i++)
            af[i] = *(const bf16x8*)&Ash[(wm * 64 + i * 16 + lr) * 32 + quad * 8];
#pragma unroll
        for (int j = 0; j < 4; j++)
            bw[j] = *(const bf16x8*)&Bsh[(wn * 64 + j * 16 + lr) * 32 + quad * 8];

#pragma unroll
        for (int i = 0; i < 4; i++)
#pragma unroll
            for (int j = 0; j < 4; j++)
                acc[i][j] = MFMA16(af[i], bw[j], acc[i][j]);
    }

    // epilogue: C/D row = quad*4+r (m-side), col = lr (n-side)
#pragma unroll
    for (int i = 0; i < 4; i++) {
#pragma unroll
        for (int j = 0; j < 4; j++) {
            const int n = n0 + wn * 64 + j * 16 + lr;
#pragma unroll
            for (int r = 0; r < 4; r++) {
                const int m = m0 + wm * 64 + i * 16 + quad * 4 + r;
                float val = (acc[i][j][r] + ((MODE == 2) ? bias[m] : bias[n])) * scale;
                if (MODE == 0) {
                    const int b = m >> 11, s = m & 2047, h = n >> 6, d = n & 63;
                    ((unsigned short*)Cv)[(((size_t)(b * 16 + h) * 2048 + s) << 6) + d] = f2bf(val);
                } else if (MODE == 1) {
                    ((float*)Cv)[(size_t)m * 1024 + n] = val;
                } else {
                    const int h = m >> 6, d = m & 63, b = n >> 11, s = n & 2047;
                    ((unsigned short*)Cv)[((size_t)(b * 16 + h) * 64 + d) * 2048 + s] = f2bf(val);
                }
            }
        }
    }
}

// ---------------------------------------------------------------------------
// Flash attention (sum-only softmax). Qh,Kh [B,H,S,64]; Vt [B,H,64,S] bf16.
// ctx out [B,S,1024] bf16. Grid (16,64), 4 waves, 32 q/wave, BK=64.
// LDS rows stride KS=72 shorts (144 B: b128-aligned, conflict-free patterns).
//
// Swapped QK^T (T12): lane (quad,lr) holds S[k=16*nt+4*quad+r][q=lr]; P stays
// in registers, PV A-frags rebuilt via cvt_pk + permlane32/16_swap (no Psh).
// Qh comes pre-scaled by 0.125*log2e -> p = exp2(s) directly (v_exp_f32).
//
// 32 q/wave: two 16-row Q tiles per wave share each K/V fragment read from
// LDS (read once, 2 MFMAs) -> LDS read bytes per unit work halved; block
// count halved (global loads, barriers, staging writes likewise).
//
// T14 async-stage: regs for tile kb+64 loaded right after kb's ds_write;
// consumed at next iteration's ds_write -> compute phase hides HBM latency.
// ---------------------------------------------------------------------------
__global__ __launch_bounds__(256) void attn_kernel(
    const unsigned short* __restrict__ Qh,
    const unsigned short* __restrict__ Kh,
    const unsigned short* __restrict__ Vt,
    unsigned short* __restrict__ ctx)
{
    constexpr int KS = 72;
    __shared__ unsigned short Ksh[64 * KS];     // [k][d]
    __shared__ unsigned short Vts[64 * KS];     // [d][k]

    const int t    = threadIdx.x;
    const int w    = t >> 6;
    const int lane = t & 63;
    const int lr   = lane & 15, quad = lane >> 4;

    const int bh = blockIdx.y, qblk = blockIdx.x;
    const size_t base = (size_t)bh * 2048 * 64;
    const unsigned short* Qp = Qh + base;
    const unsigned short* Kg = Kh + base + (size_t)lane * 64 + w * 16;
    const unsigned short* Vg = Vt + base + (size_t)lane * 2048 + w * 16;

    const int q0 = qblk * 128 + w * 32;
    const unsigned short* qr0 = Qp + (size_t)(q0 + lr) * 64;
    const unsigned short* qr1 = Qp + (size_t)(q0 + 16 + lr) * 64;
    bf16x8 aq0 = *(const bf16x8*)(qr0 + quad * 8);
    bf16x8 aq1 = *(const bf16x8*)(qr0 + 32 + quad * 8);
    bf16x8 aq2 = *(const bf16x8*)(qr1 + quad * 8);
    bf16x8 aq3 = *(const bf16x8*)(qr1 + 32 + quad * 8);

    f32x4 Of0[4] = {}, Of1[4] = {};
    float ls0 = 0.f, ls1 = 0.f;

    // prologue: prefetch tile kb=0
    s16x8 kv0 = *(const s16x8*)(Kg);
    s16x8 kv1 = *(const s16x8*)(Kg + 8);
    s16x8 vv0 = *(const s16x8*)(Vg);
    s16x8 vv1 = *(const s16x8*)(Vg + 8);

    for (int kb = 0; kb < 2048; kb += 64) {
        __syncthreads();   // prior iteration's LDS reads complete
        *(s16x8*)&Ksh[lane * KS + w * 16]     = kv0;
        *(s16x8*)&Ksh[lane * KS + w * 16 + 8] = kv1;
        *(s16x8*)&Vts[lane * KS + w * 16]     = vv0;
        *(s16x8*)&Vts[lane * KS + w * 16 + 8] = vv1;

        // issue next tile's loads now; consumed at NEXT iteration's ds_write
        const int kn = (kb + 64) & 2047;     // wraps to 0 on last iter (unused)
        kv0 = *(const s16x8*)(Kg + (size_t)kn * 64);
        kv1 = *(const s16x8*)(Kg + (size_t)kn * 64 + 8);
        vv0 = *(const s16x8*)(Vg + kn);
        vv1 = *(const s16x8*)(Vg + kn + 8);

        __syncthreads();   // staged tile visible

        // ---- swapped QK^T: each K fragment read once, used by both q-tiles
        f32x4 pe0[4], pe1[4];
#pragma unroll
        for (int nt = 0; nt < 4; nt++) {
            const unsigned short* kr = &Ksh[(16 * nt + lr) * KS + quad * 8];
            bf16x8 k0 = *(const bf16x8*)kr;
            bf16x8 k1 = *(const bf16x8*)(kr + 32);
            f32x4 c0 = {}, c1 = {};
            c0 = MFMA16(k0, aq0, c0); c0 = MFMA16(k1, aq1, c0);
            c1 = MFMA16(k0, aq2, c1); c1 = MFMA16(k1, aq3, c1);
            f32x4 p0, p1;
#pragma unroll
            for (int r = 0; r < 4; r++) p0[r] = exp2_fast(c0[r]);
#pragma unroll
            for (int r = 0; r < 4; r++) p1[r] = exp2_fast(c1[r]);
            ls0 += (p0[0] + p0[1]) + (p0[2] + p0[3]);
            ls1 += (p1[0] + p1[1]) + (p1[2] + p1[3]);
            pe0[nt] = p0; pe1[nt] = p1;
        }

        // ---- PV A-fragments in-register (no LDS round-trip)
        bf16x8 pf00, pf01, pf10, pf11;
        pack_pf(pe0, pf00, pf01);
        pack_pf(pe1, pf10, pf11);

        // ---- PV : each V fragment read once, used by both q-tiles
#pragma unroll
        for (int dt = 0; dt < 4; dt++) {
            const unsigned short* vr = &Vts[(dt * 16 + lr) * KS + quad * 8];
            bf16x8 v0 = *(const bf16x8*)vr;
            bf16x8 v1 = *(const bf16x8*)(vr + 32);
            Of0[dt] = MFMA16(pf00, v0, Of0[dt]);
            Of0[dt] = MFMA16(pf01, v1, Of0[dt]);
            Of1[dt] = MFMA16(pf10, v0, Of1[dt]);
            Of1[dt] = MFMA16(pf11, v1, Of1[dt]);
        }
    }

    // lane's ls covers k={16nt+4quad+r} for q=lr; sum across quads -> all k
    ls0 += __shfl_xor(ls0, 16);
    ls0 += __shfl_xor(ls0, 32);
    ls1 += __shfl_xor(ls1, 16);
    ls1 += __shfl_xor(ls1, 32);

    const int b = bh >> 4, h = bh & 15;
#pragma unroll
    for (int r = 0; r < 4; r++) {
        const float inv0 = 1.0f / __shfl(ls0, quad * 4 + r, 64);
        const int qa = q0 + quad * 4 + r;
        unsigned short* cp0 = ctx + ((size_t)b * 2048 + qa) * 1024 + h * 64;
#pragma unroll
        for (int dt = 0; dt < 4; dt++)
            cp0[dt * 16 + lr] = f2bf(Of0[dt][r] * inv0);

        const float inv1 = 1.0f / __shfl(ls1, quad * 4 + r, 64);
        const int qb = q0 + 16 + quad * 4 + r;
        unsigned short* cp1 = ctx + ((size_t)b * 2048 + qb) * 1024 + h * 64;
#pragma unroll
        for (int dt = 0; dt < 4; dt++)
            cp1[dt * 16 + lr] = f2bf(Of1[dt][r] * inv1);
    }
}

// ---------------------------------------------------------------------------
extern "C" void kernel_launch(void* const* d_in, const int* in_sizes, int n_in,
                              void* d_out, int out_size, void* d_ws, size_t ws_size,
                              hipStream_t stream) {
    const float* Q  = (const float*)d_in[0];
    const float* K  = (const float*)d_in[1];
    const float* V  = (const float*)d_in[2];
    const float* Wq = (const float*)d_in[3];
    const float* bq = (const float*)d_in[4];
    const float* Wk = (const float*)d_in[5];
    const float* bk = (const float*)d_in[6];
    const float* Wv = (const float*)d_in[7];
    const float* bv = (const float*)d_in[8];
    const float* Wo = (const float*)d_in[9];
    const float* bo = (const float*)d_in[10];

    // workspace (bf16 elements). Xb reused serially for Q,K,V; Ctx aliases Xb.
    const size_t EB = (size_t)8192 * 1024;   // big tensor elems
    const size_t EW = (size_t)1024 * 1024;   // weight elems
    unsigned short* Xb  = (unsigned short*)d_ws;
    unsigned short* Wqb = Xb  + EB;
    unsigned short* Wkb = Wqb + EW;
    unsigned short* Wvb = Wkb + EW;
    unsigned short* Wob = Wvb + EW;
    unsigned short* Qh  = Wob + EW;
    unsigned short* Kh  = Qh  + EB;
    unsigned short* Vtw = Kh  + EB;
    unsigned short* Ctx = Xb;                 // Xb dead after V-GEMM

    const int n8b = (int)(EB / 8);            // 1048576
    const int n8w = (int)(EW / 8);            // 131072

    // 1/sqrt(64) * log2(e): scores*log2e folded into Qh so attn uses exp2
    const float QSCALE = 0.125f * 1.44269504088896340736f;

    cvt_kernel<<<n8w / 256, 256, 0, stream>>>(Wq, Wqb, n8w);
    cvt_kernel<<<n8w / 256, 256, 0, stream>>>(Wk, Wkb, n8w);
    cvt_kernel<<<n8w / 256, 256, 0, stream>>>(Wv, Wvb, n8w);
    cvt_kernel<<<n8w / 256, 256, 0, stream>>>(Wo, Wob, n8w);

    dim3 tb(256), gP(8, 64), gT(64, 8);

    cvt_kernel<<<n8b / 256, 256, 0, stream>>>(Q, Xb, n8b);
    gemm_bf16<0><<<gP, tb, 0, stream>>>(Xb, Wqb, bq, Qh, QSCALE);

    cvt_kernel<<<n8b / 256, 256, 0, stream>>>(K, Xb, n8b);
    gemm_bf16<0><<<gP, tb, 0, stream>>>(Xb, Wkb, bk, Kh, 1.0f);

    cvt_kernel<<<n8b / 256, 256, 0, stream>>>(V, Xb, n8b);
    gemm_bf16<2><<<gT, tb, 0, stream>>>(Wvb, Xb, bv, Vtw, 1.0f);   // V^T layout

    attn_kernel<<<dim3(16, 64), tb, 0, stream>>>(Qh, Kh, Vtw, Ctx);

    gemm_bf16<1><<<gP, tb, 0, stream>>>(Ctx, Wob, bo, (float*)d_out, 1.0f);
}

// Round 5
// 358.268 us; speedup vs baseline: 1.2788x; 1.0411x over previous
//
#include <hip/hip_runtime.h>
#include <hip/hip_bf16.h>

// ---------------------------------------------------------------------------
// MHA forward: fp32 I/O, bf16 MFMA compute. B=4,S=2048,D=1024,H=16,DK=64.
//   0. convert all inputs fp32 -> bf16 (one merged weight-cvt launch; Xb
//      staging buffer reused serially for Q,K,V)
//   1. Qh = (Q@Wq^T+bq)*0.125*log2e -> [B,H,S,64]  (scale folded for exp2)
//   2. Kh likewise (scale=1); Vt = (V@Wv^T+bv)^T -> [B,H,64,S]
//   3. flash attention (sum-only softmax; swapped QK^T, in-register P,
//      T14 async-stage, 32 q-rows/wave)
//   4. out = ctx@Wo^T+bo (fp32 store)
// GEMM K-loop: LDS double-buffer + counted vmcnt(4) (never drain in loop) +
// raw s_barrier -> next tile's global_load_lds stay in flight across the
// whole compute phase. T1 chunked XCD swizzle (MODE 0/1): each XCD gets 8
// contiguous A-panels (2MB) + full W (2MB) = L2-resident operands.
// ---------------------------------------------------------------------------

typedef float  f32x4  __attribute__((ext_vector_type(4)));
typedef __bf16 bf16x8 __attribute__((ext_vector_type(8)));
typedef short  s16x8  __attribute__((ext_vector_type(8)));
typedef int    i32x4  __attribute__((ext_vector_type(4)));

#define MFMA16(a,b,c) __builtin_amdgcn_mfma_f32_16x16x32_bf16((a),(b),(c),0,0,0)

__device__ __forceinline__ unsigned short f2bf(float f) {
    union { float f; unsigned u; } v; v.f = f;
    unsigned r = v.u + 0x7fffu + ((v.u >> 16) & 1u);   // RNE
    return (unsigned short)(r >> 16);
}

__device__ __forceinline__ s16x8 cvt8(const float* __restrict__ p) {
    f32x4 x = *(const f32x4*)p;
    f32x4 y = *(const f32x4*)(p + 4);
    s16x8 r;
    r[0] = (short)f2bf(x[0]); r[1] = (short)f2bf(x[1]);
    r[2] = (short)f2bf(x[2]); r[3] = (short)f2bf(x[3]);
    r[4] = (short)f2bf(y[0]); r[5] = (short)f2bf(y[1]);
    r[6] = (short)f2bf(y[2]); r[7] = (short)f2bf(y[3]);
    return r;
}

// async global->LDS, 16 B per lane; LDS dest = wave-uniform base + lane*16
__device__ __forceinline__ void gl_lds16(const void* g, void* l) {
    __builtin_amdgcn_global_load_lds(
        (const __attribute__((address_space(1))) unsigned int*)g,
        (__attribute__((address_space(3))) unsigned int*)l, 16, 0, 0);
}

// raw v_exp_f32: D = 2^S0
__device__ __forceinline__ float exp2_fast(float x) {
    float r;
    asm("v_exp_f32 %0, %1" : "=v"(r) : "v"(x));
    return r;
}

// pack 2 f32 -> 1 dword of 2 bf16 (RNE). D[15:0]=bf16(lo), D[31:16]=bf16(hi)
__device__ __forceinline__ int cvtpk_bf16(float lo, float hi) {
    int r;
    asm("v_cvt_pk_bf16_f32 %0, %1, %2" : "=v"(r) : "v"(lo), "v"(hi));
    return r;
}
// a.row1(32 lanes) <-> b.row0: a'=[a.lo32,b.lo32], b'=[a.hi32,b.hi32]
__device__ __forceinline__ void plswap32(int& a, int& b) {
    asm("v_permlane32_swap_b32 %0, %1" : "+v"(a), "+v"(b));
}
// odd 16-rows of a <-> even 16-rows of b:
// a'=[a.r0,b.r0,a.r2,b.r2], b'=[a.r1,b.r1,a.r3,b.r3]
__device__ __forceinline__ void plswap16(int& a, int& b) {
    asm("v_permlane16_swap_b32 %0, %1" : "+v"(a), "+v"(b));
}

// P-row (lane-local, S^T layout) -> two PV A-fragment dwords x2
__device__ __forceinline__ void pack_pf(const f32x4 pe[4], bf16x8& pf0, bf16x8& pf1) {
    int a0 = cvtpk_bf16(pe[0][0], pe[0][1]);
    int a1 = cvtpk_bf16(pe[0][2], pe[0][3]);
    int b0 = cvtpk_bf16(pe[1][0], pe[1][1]);
    int b1 = cvtpk_bf16(pe[1][2], pe[1][3]);
    plswap32(a0, b0); plswap32(a1, b1);
    plswap16(a0, b0); plswap16(a1, b1);
    i32x4 f0; f0[0] = a0; f0[1] = a1; f0[2] = b0; f0[3] = b1;
    int c0 = cvtpk_bf16(pe[2][0], pe[2][1]);
    int c1 = cvtpk_bf16(pe[2][2], pe[2][3]);
    int d0 = cvtpk_bf16(pe[3][0], pe[3][1]);
    int d1 = cvtpk_bf16(pe[3][2], pe[3][3]);
    plswap32(c0, d0); plswap32(c1, d1);
    plswap16(c0, d0); plswap16(c1, d1);
    i32x4 f1; f1[0] = c0; f1[1] = c1; f1[2] = d0; f1[3] = d1;
    pf0 = __builtin_bit_cast(bf16x8, f0);
    pf1 = __builtin_bit_cast(bf16x8, f1);
}

// ---------------------------------------------------------------------------
__global__ __launch_bounds__(256) void cvt_kernel(
    const float* __restrict__ src, unsigned short* __restrict__ dst, int n8)
{
    int i = blockIdx.x * 256 + threadIdx.x;
    if (i < n8) *(s16x8*)(dst + (size_t)i * 8) = cvt8(src + (size_t)i * 8);
}

// all four 1024x1024 weights in one launch (512 blocks per weight)
__global__ __launch_bounds__(256) void wcvt_kernel(
    const float* __restrict__ s0, const float* __restrict__ s1,
    const float* __restrict__ s2, const float* __restrict__ s3,
    unsigned short* __restrict__ d0, unsigned short* __restrict__ d1,
    unsigned short* __restrict__ d2, unsigned short* __restrict__ d3)
{
    const int which = blockIdx.x >> 9;
    const int i = (blockIdx.x & 511) * 256 + threadIdx.x;
    const float* s = (which == 0) ? s0 : (which == 1) ? s1 : (which == 2) ? s2 : s3;
    unsigned short* d = (which == 0) ? d0 : (which == 1) ? d1 : (which == 2) ? d2 : d3;
    *(s16x8*)(d + (size_t)i * 8) = cvt8(s + (size_t)i * 8);
}

// ---------------------------------------------------------------------------
// bf16 NT GEMM, 128x128 tile, BK=32, global_load_lds staging.
// D[m,n] = (sum_k A[m,k]*W[n,k] + bias) * scale
// MODE 0: bias[n]; head-split store [B,H,S,64]           (Q,K projections)
// MODE 1: bias[n]; flat fp32 store [M,1024]              (output projection)
// MODE 2: bias[m]; transposed store [B,H,64,S]           (V: A=Wv, W=V)
//
// K-loop: LDS double-buffer; tile k+1's 4 gl_lds issued BEFORE waiting on
// tile k (s_waitcnt vmcnt(4): the 4 newest stay in flight across both
// barriers + the MFMA phase). Raw s_barrier (no implicit vmcnt(0) drain).
// MODE 0/1 grid (8,64): chunked XCD swizzle -> XCD k owns orig blocks
// [64k,64k+64) = 8 A-panels x all 8 n-blocks; A(2MB)+W(2MB) L2-resident.
// MODE 2: natural map already co-locates V-panel sharers (stride 64 = 0 mod 8).
// ---------------------------------------------------------------------------
template <int MODE>
__global__ __launch_bounds__(256) void gemm_bf16(
    const unsigned short* __restrict__ A,
    const unsigned short* __restrict__ W,
    const float* __restrict__ bias,
    void* __restrict__ Cv, float scale)
{
    constexpr int K = 1024;
    __shared__ unsigned short Ash[2 * 128 * 32];   // [buf][row][k]
    __shared__ unsigned short Bsh[2 * 128 * 32];

    const int t    = threadIdx.x;
    const int w    = t >> 6;
    const int lane = t & 63;
    const int wm   = w >> 1, wn = w & 1;
    const int lr   = lane & 15, quad = lane >> 4;

    int m0, n0;
    if (MODE == 2) {
        m0 = blockIdx.y * 128;
        n0 = blockIdx.x * 128;
    } else {
        const int bid  = blockIdx.y * 8 + blockIdx.x;   // hw flat id, x fastest
        const int orig = (bid & 7) * 64 + (bid >> 3);   // chunked XCD swizzle
        n0 = (orig & 7) * 128;
        m0 = (orig >> 3) * 128;
    }

    // staging chunk c = t: LDS offset c*16 B -> row = t>>2 (32-short rows), kchunk=(t&3)*8
    const int srow = t >> 2;
    const int skp  = (t & 3) * 8;

    const unsigned short* Ap0 = A + (size_t)(m0 + srow) * K + skp;
    const unsigned short* Ap1 = Ap0 + (size_t)64 * K;
    const unsigned short* Wp0 = W + (size_t)(n0 + srow) * K + skp;
    const unsigned short* Wp1 = Wp0 + (size_t)64 * K;
    unsigned short* lA0 = &Ash[w * 512];           // wave-uniform bases (buf 0)
    unsigned short* lA1 = &Ash[2048 + w * 512];
    unsigned short* lB0 = &Bsh[w * 512];
    unsigned short* lB1 = &Bsh[2048 + w * 512];

#define STAGE(buf, k0) do {                       \
        gl_lds16(Ap0 + (k0), lA0 + (buf) * 4096); \
        gl_lds16(Ap1 + (k0), lA1 + (buf) * 4096); \
        gl_lds16(Wp0 + (k0), lB0 + (buf) * 4096); \
        gl_lds16(Wp1 + (k0), lB1 + (buf) * 4096); \
    } while (0)

    f32x4 acc[4][4] = {};

    STAGE(0, 0);                         // prologue: tile 0 in flight
    int cur = 0;

    for (int k0 = 0; k0 < K; k0 += 32) {
        if (k0 + 32 < K) {
            STAGE(cur ^ 1, k0 + 32);     // prefetch next tile (stays in flight)
            asm volatile("s_waitcnt vmcnt(4)" ::: "memory");   // current tile done
        } else {
            asm volatile("s_waitcnt vmcnt(0)" ::: "memory");   // last tile: drain
        }
        __builtin_amdgcn_s_barrier();    // current tile visible to all waves
        __builtin_amdgcn_sched_barrier(0);

        bf16x8 af[4], bw[4];
#pragma unroll
        for (int i = 0; i < 4; i++)
            af[i] = *(const bf16x8*)&Ash[cur * 4096 + (wm * 64 + i * 16 + lr) * 32 + quad * 8];
#pragma unroll
        for (int j = 0; j < 4; j++)
            bw[j] = *(const bf16x8*)&Bsh[cur * 4096 + (wn * 64 + j * 16 + lr) * 32 + quad * 8];

#pragma unroll
        for (int i = 0; i < 4; i++)
#pragma unroll
            for (int j = 0; j < 4; j++)
                acc[i][j] = MFMA16(af[i], bw[j], acc[i][j]);

        __builtin_amdgcn_sched_barrier(0);
        __builtin_amdgcn_s_barrier();    // all waves done reading buf cur
        cur ^= 1;
    }
#undef STAGE

    // epilogue: C/D row = quad*4+r (m-side), col = lr (n-side)
#pragma unroll
    for (int i = 0; i < 4; i++) {
#pragma unroll
        for (int j = 0; j < 4; j++) {
            const int n = n0 + wn * 64 + j * 16 + lr;
#pragma unroll
            for (int r = 0; r < 4; r++) {
                const int m = m0 + wm * 64 + i * 16 + quad * 4 + r;
                float val = (acc[i][j][r] + ((MODE == 2) ? bias[m] : bias[n])) * scale;
                if (MODE == 0) {
                    const int b = m >> 11, s = m & 2047, h = n >> 6, d = n & 63;
                    ((unsigned short*)Cv)[(((size_t)(b * 16 + h) * 2048 + s) << 6) + d] = f2bf(val);
                } else if (MODE == 1) {
                    ((float*)Cv)[(size_t)m * 1024 + n] = val;
                } else {
                    const int h = m >> 6, d = m & 63, b = n >> 11, s = n & 2047;
                    ((unsigned short*)Cv)[((size_t)(b * 16 + h) * 64 + d) * 2048 + s] = f2bf(val);
                }
            }
        }
    }
}

// ---------------------------------------------------------------------------
// Flash attention (sum-only softmax). Qh,Kh [B,H,S,64]; Vt [B,H,64,S] bf16.
// ctx out [B,S,1024] bf16. Grid (16,64), 4 waves, 32 q/wave, BK=64.
// LDS rows stride KS=72 shorts (144 B: b128-aligned, conflict-free patterns).
//
// Swapped QK^T (T12): lane (quad,lr) holds S[k=16*nt+4*quad+r][q=lr]; P stays
// in registers, PV A-frags rebuilt via cvt_pk + permlane32/16_swap (no Psh).
// Qh comes pre-scaled by 0.125*log2e -> p = exp2(s) directly (v_exp_f32).
//
// 32 q/wave: two 16-row Q tiles per wave share each K/V fragment read from
// LDS (read once, 2 MFMAs) -> LDS read bytes per unit work halved; block
// count halved (global loads, barriers, staging writes likewise).
//
// T14 async-stage: regs for tile kb+64 loaded right after kb's ds_write;
// consumed at next iteration's ds_write -> compute phase hides HBM latency.
// ---------------------------------------------------------------------------
__global__ __launch_bounds__(256) void attn_kernel(
    const unsigned short* __restrict__ Qh,
    const unsigned short* __restrict__ Kh,
    const unsigned short* __restrict__ Vt,
    unsigned short* __restrict__ ctx)
{
    constexpr int KS = 72;
    __shared__ unsigned short Ksh[64 * KS];     // [k][d]
    __shared__ unsigned short Vts[64 * KS];     // [d][k]

    const int t    = threadIdx.x;
    const int w    = t >> 6;
    const int lane = t & 63;
    const int lr   = lane & 15, quad = lane >> 4;

    const int bh = blockIdx.y, qblk = blockIdx.x;
    const size_t base = (size_t)bh * 2048 * 64;
    const unsigned short* Qp = Qh + base;
    const unsigned short* Kg = Kh + base + (size_t)lane * 64 + w * 16;
    const unsigned short* Vg = Vt + base + (size_t)lane * 2048 + w * 16;

    const int q0 = qblk * 128 + w * 32;
    const unsigned short* qr0 = Qp + (size_t)(q0 + lr) * 64;
    const unsigned short* qr1 = Qp + (size_t)(q0 + 16 + lr) * 64;
    bf16x8 aq0 = *(const bf16x8*)(qr0 + quad * 8);
    bf16x8 aq1 = *(const bf16x8*)(qr0 + 32 + quad * 8);
    bf16x8 aq2 = *(const bf16x8*)(qr1 + quad * 8);
    bf16x8 aq3 = *(const bf16x8*)(qr1 + 32 + quad * 8);

    f32x4 Of0[4] = {}, Of1[4] = {};
    float ls0 = 0.f, ls1 = 0.f;

    // prologue: prefetch tile kb=0
    s16x8 kv0 = *(const s16x8*)(Kg);
    s16x8 kv1 = *(const s16x8*)(Kg + 8);
    s16x8 vv0 = *(const s16x8*)(Vg);
    s16x8 vv1 = *(const s16x8*)(Vg + 8);

    for (int kb = 0; kb < 2048; kb += 64) {
        __syncthreads();   // prior iteration's LDS reads complete
        *(s16x8*)&Ksh[lane * KS + w * 16]     = kv0;
        *(s16x8*)&Ksh[lane * KS + w * 16 + 8] = kv1;
        *(s16x8*)&Vts[lane * KS + w * 16]     = vv0;
        *(s16x8*)&Vts[lane * KS + w * 16 + 8] = vv1;

        // issue next tile's loads now; consumed at NEXT iteration's ds_write
        const int kn = (kb + 64) & 2047;     // wraps to 0 on last iter (unused)
        kv0 = *(const s16x8*)(Kg + (size_t)kn * 64);
        kv1 = *(const s16x8*)(Kg + (size_t)kn * 64 + 8);
        vv0 = *(const s16x8*)(Vg + kn);
        vv1 = *(const s16x8*)(Vg + kn + 8);

        __syncthreads();   // staged tile visible

        // ---- swapped QK^T: each K fragment read once, used by both q-tiles
        f32x4 pe0[4], pe1[4];
#pragma unroll
        for (int nt = 0; nt < 4; nt++) {
            const unsigned short* kr = &Ksh[(16 * nt + lr) * KS + quad * 8];
            bf16x8 k0 = *(const bf16x8*)kr;
            bf16x8 k1 = *(const bf16x8*)(kr + 32);
            f32x4 c0 = {}, c1 = {};
            c0 = MFMA16(k0, aq0, c0); c0 = MFMA16(k1, aq1, c0);
            c1 = MFMA16(k0, aq2, c1); c1 = MFMA16(k1, aq3, c1);
            f32x4 p0, p1;
#pragma unroll
            for (int r = 0; r < 4; r++) p0[r] = exp2_fast(c0[r]);
#pragma unroll
            for (int r = 0; r < 4; r++) p1[r] = exp2_fast(c1[r]);
            ls0 += (p0[0] + p0[1]) + (p0[2] + p0[3]);
            ls1 += (p1[0] + p1[1]) + (p1[2] + p1[3]);
            pe0[nt] = p0; pe1[nt] = p1;
        }

        // ---- PV A-fragments in-register (no LDS round-trip)
        bf16x8 pf00, pf01, pf10, pf11;
        pack_pf(pe0, pf00, pf01);
        pack_pf(pe1, pf10, pf11);

        // ---- PV : each V fragment read once, used by both q-tiles
#pragma unroll
        for (int dt = 0; dt < 4; dt++) {
            const unsigned short* vr = &Vts[(dt * 16 + lr) * KS + quad * 8];
            bf16x8 v0 = *(const bf16x8*)vr;
            bf16x8 v1 = *(const bf16x8*)(vr + 32);
            Of0[dt] = MFMA16(pf00, v0, Of0[dt]);
            Of0[dt] = MFMA16(pf01, v1, Of0[dt]);
            Of1[dt] = MFMA16(pf10, v0, Of1[dt]);
            Of1[dt] = MFMA16(pf11, v1, Of1[dt]);
        }
    }

    // lane's ls covers k={16nt+4quad+r} for q=lr; sum across quads -> all k
    ls0 += __shfl_xor(ls0, 16);
    ls0 += __shfl_xor(ls0, 32);
    ls1 += __shfl_xor(ls1, 16);
    ls1 += __shfl_xor(ls1, 32);

    const int b = bh >> 4, h = bh & 15;
#pragma unroll
    for (int r = 0; r < 4; r++) {
        const float inv0 = 1.0f / __shfl(ls0, quad * 4 + r, 64);
        const int qa = q0 + quad * 4 + r;
        unsigned short* cp0 = ctx + ((size_t)b * 2048 + qa) * 1024 + h * 64;
#pragma unroll
        for (int dt = 0; dt < 4; dt++)
            cp0[dt * 16 + lr] = f2bf(Of0[dt][r] * inv0);

        const float inv1 = 1.0f / __shfl(ls1, quad * 4 + r, 64);
        const int qb = q0 + 16 + quad * 4 + r;
        unsigned short* cp1 = ctx + ((size_t)b * 2048 + qb) * 1024 + h * 64;
#pragma unroll
        for (int dt = 0; dt < 4; dt++)
            cp1[dt * 16 + lr] = f2bf(Of1[dt][r] * inv1);
    }
}

// ---------------------------------------------------------------------------
extern "C" void kernel_launch(void* const* d_in, const int* in_sizes, int n_in,
                              void* d_out, int out_size, void* d_ws, size_t ws_size,
                              hipStream_t stream) {
    const float* Q  = (const float*)d_in[0];
    const float* K  = (const float*)d_in[1];
    const float* V  = (const float*)d_in[2];
    const float* Wq = (const float*)d_in[3];
    const float* bq = (const float*)d_in[4];
    const float* Wk = (const float*)d_in[5];
    const float* bk = (const float*)d_in[6];
    const float* Wv = (const float*)d_in[7];
    const float* bv = (const float*)d_in[8];
    const float* Wo = (const float*)d_in[9];
    const float* bo = (const float*)d_in[10];

    // workspace (bf16 elements). Xb reused serially for Q,K,V; Ctx aliases Xb.
    const size_t EB = (size_t)8192 * 1024;   // big tensor elems
    const size_t EW = (size_t)1024 * 1024;   // weight elems
    unsigned short* Xb  = (unsigned short*)d_ws;
    unsigned short* Wqb = Xb  + EB;
    unsigned short* Wkb = Wqb + EW;
    unsigned short* Wvb = Wkb + EW;
    unsigned short* Wob = Wvb + EW;
    unsigned short* Qh  = Wob + EW;
    unsigned short* Kh  = Qh  + EB;
    unsigned short* Vtw = Kh  + EB;
    unsigned short* Ctx = Xb;                 // Xb dead after V-GEMM

    const int n8b = (int)(EB / 8);            // 1048576

    // 1/sqrt(64) * log2(e): scores*log2e folded into Qh so attn uses exp2
    const float QSCALE = 0.125f * 1.44269504088896340736f;

    wcvt_kernel<<<2048, 256, 0, stream>>>(Wq, Wk, Wv, Wo, Wqb, Wkb, Wvb, Wob);

    dim3 tb(256), gP(8, 64), gT(64, 8);

    cvt_kernel<<<n8b / 256, 256, 0, stream>>>(Q, Xb, n8b);
    gemm_bf16<0><<<gP, tb, 0, stream>>>(Xb, Wqb, bq, Qh, QSCALE);

    cvt_kernel<<<n8b / 256, 256, 0, stream>>>(K, Xb, n8b);
    gemm_bf16<0><<<gP, tb, 0, stream>>>(Xb, Wkb, bk, Kh, 1.0f);

    cvt_kernel<<<n8b / 256, 256, 0, stream>>>(V, Xb, n8b);
    gemm_bf16<2><<<gT, tb, 0, stream>>>(Wvb, Xb, bv, Vtw, 1.0f);   // V^T layout

    attn_kernel<<<dim3(16, 64), tb, 0, stream>>>(Qh, Kh, Vtw, Ctx);

    gemm_bf16<1><<<gP, tb, 0, stream>>>(Ctx, Wob, bo, (float*)d_out, 1.0f);
}